// Round 7
// baseline (83.580 us; speedup 1.0000x reference)
//
#include <hip/hip_runtime.h>

// QuantumKernelMethod, single launch with in-grid barrier (RMW protocol).
// out[i][j] = |tr(Q_i M_j)|, Q_i = phi phi^dag (phi = V(a_i)|0>),
// M_j = I - 2 P_j, P_j = sum_{p=8..15} w_p w_p^dag (8 basis sims per y).
// Hermitian pack K=256: dot(S_Q,S_M) = tr(QM) -> bf16 MFMA GEMM 1024x1024x256.
// Producers: blocks 0..31 (M), 32..35 (Q), 1 sim/thread, no redundancy.
// Barrier lessons: R5 ACQUIRE-poll = invalidate storm (106us). R6 RELAXED
// poll/store = non-coherent across XCD L2s, ~50us eventual visibility (62us).
// R7: RMW atomics both ends (exchange-release / fetch_or-relaxed) — RMWs
// execute at the coherence point, fresh every poll, no invalidates. One
// acquire fence after the break for Q/M data. Each consumer waits on only the
// 3 producer flags it depends on (2 M-blocks + 1 Q-block).

#define NA 1024
#define NB 1024
#define KD 256
#define RT2 1.41421356237f
#define MAGIC 0x5AC0FFEEu
#define WSTR 17     // LDS sim-row stride (floats)

typedef __attribute__((ext_vector_type(8))) short bf16x8;
typedef __attribute__((ext_vector_type(4))) float f32x4;

__device__ __forceinline__ unsigned short f2bf(float x) {
    union { float f; unsigned u; } v; v.f = x;
    unsigned r = v.u + 0x7fffu + ((v.u >> 16) & 1u);  // RNE
    return (unsigned short)(r >> 16);
}

__device__ __forceinline__ uint4 pack8(const float* f) {
    uint4 u;
    u.x = (unsigned)f2bf(f[0]) | ((unsigned)f2bf(f[1]) << 16);
    u.y = (unsigned)f2bf(f[2]) | ((unsigned)f2bf(f[3]) << 16);
    u.z = (unsigned)f2bf(f[4]) | ((unsigned)f2bf(f[5]) << 16);
    u.w = (unsigned)f2bf(f[6]) | ((unsigned)f2bf(f[7]) << 16);
    return u;
}

// State: 16 complex amps, flat index = b0*8+b1*4+b2*2+b3 (wire w -> bit 3-w)
__device__ __forceinline__ void ry_gate(float* sr, float* si, int w, float t) {
    float s, c; __sincosf(0.5f * t, &s, &c);
    int st = 8 >> w;
    #pragma unroll
    for (int b = 0; b < 16; ++b) {
        if (b & st) continue;
        int j = b | st;
        float r0 = sr[b], i0 = si[b], r1 = sr[j], i1 = si[j];
        sr[b] = c * r0 - s * r1;  si[b] = c * i0 - s * i1;
        sr[j] = s * r0 + c * r1;  si[j] = s * i0 + c * i1;
    }
}

__device__ __forceinline__ void rx_gate(float* sr, float* si, int w, float t) {
    float s, c; __sincosf(0.5f * t, &s, &c);
    int st = 8 >> w;
    #pragma unroll
    for (int b = 0; b < 16; ++b) {
        if (b & st) continue;
        int j = b | st;
        float r0 = sr[b], i0 = si[b], r1 = sr[j], i1 = si[j];
        sr[b] = c * r0 + s * i1;  si[b] = c * i0 - s * r1;
        sr[j] = c * r1 + s * i0;  si[j] = c * i1 - s * r0;
    }
}

__device__ __forceinline__ void rz_gate(float* sr, float* si, int w, float t) {
    float s, c; __sincosf(0.5f * t, &s, &c);
    int st = 8 >> w;
    #pragma unroll
    for (int b = 0; b < 16; ++b) {
        if (b & st) continue;
        int j = b | st;
        float r0 = sr[b], i0 = si[b], r1 = sr[j], i1 = si[j];
        sr[b] = c * r0 + s * i0;  si[b] = c * i0 - s * r0;
        sr[j] = c * r1 - s * i1;  si[j] = c * i1 + s * r1;
    }
}

__device__ __forceinline__ void cnot_gate(float* sr, float* si, int cw, int tw) {
    int cs = 8 >> cw, ts = 8 >> tw;
    #pragma unroll
    for (int b = 0; b < 16; ++b) {
        if ((b & cs) && !(b & ts)) {
            int j = b | ts;
            float tr = sr[b]; sr[b] = sr[j]; sr[j] = tr;
            float ti = si[b]; si[b] = si[j]; si[j] = ti;
        }
    }
}

__device__ __forceinline__ void ansatz(float* sr, float* si, const float* vec, const float* P) {
    #pragma unroll
    for (int q = 0; q < 4; ++q) ry_gate(sr, si, q, vec[q]);
    #pragma unroll
    for (int l = 0; l < 2; ++l) {
        #pragma unroll
        for (int q = 0; q < 4; ++q) {
            rx_gate(sr, si, q, P[l * 12 + q * 3 + 0]);
            ry_gate(sr, si, q, P[l * 12 + q * 3 + 1]);
            rz_gate(sr, si, q, P[l * 12 + q * 3 + 2]);
        }
        cnot_gate(sr, si, 0, 1);
        cnot_gate(sr, si, 1, 2);
        cnot_gate(sr, si, 2, 3);
        cnot_gate(sr, si, 3, 0);
    }
}

__global__ __launch_bounds__(256) void qkm_one(
    const float* __restrict__ a, const float* __restrict__ b,
    const float* __restrict__ params,
    unsigned short* __restrict__ Q, unsigned short* __restrict__ M,
    unsigned* __restrict__ flags, float* __restrict__ out) {
    __shared__ float Wr2[256 * WSTR];
    __shared__ float Wi2[256 * WSTR];
    int tid = threadIdx.x;
    int blk = blockIdx.x;

    // Tile mapping (needed early for dependency flags).
    int xcd = blk & 7;
    int slot = blk >> 3;                 // [0,32)
    int bi = xcd * 2 + (slot >> 4);      // [0,16)
    int bj = slot & 15;                  // [0,16)

    // ---------------- Phase 1: producers ----------------
    if (blk < 36) {
        float P[24];
        #pragma unroll
        for (int j = 0; j < 24; ++j) P[j] = params[j];

        if (blk < 32) {
            // M producer: 32 y's per block, tid = y_loc*8 + p, sim state 8+p.
            int y_loc = tid >> 3, p = tid & 7;
            int y = (blk << 5) + y_loc;
            float sr[16], si[16];
            #pragma unroll
            for (int k = 0; k < 16; ++k) { sr[k] = (k == 8 + p) ? 1.f : 0.f; si[k] = 0.f; }
            float vec[4];
            #pragma unroll
            for (int q = 0; q < 4; ++q) vec[q] = b[y * 4 + q];
            ansatz(sr, si, vec, P);
            #pragma unroll
            for (int l = 0; l < 16; ++l) {
                Wr2[tid * WSTR + l] = sr[l];
                Wi2[tid * WSTR + l] = si[l];
            }
            __syncthreads();
            // Assembly: thread (y_loc, t) builds rows k0=2t, k0+1 of S_M for y.
            int t = tid & 7;
            int base = (y_loc << 3);
            int k0 = 2 * t, k1 = k0 + 1;
            float re0[16], im0[16], re1[16], im1[16];
            #pragma unroll
            for (int l = 0; l < 16; ++l) { re0[l]=0.f; im0[l]=0.f; re1[l]=0.f; im1[l]=0.f; }
            #pragma unroll
            for (int p2 = 0; p2 < 8; ++p2) {
                const float* rr = &Wr2[(base + p2) * WSTR];
                const float* ri = &Wi2[(base + p2) * WSTR];
                float wr0 = rr[k0], wi0 = ri[k0];
                float wr1 = rr[k1], wi1 = ri[k1];
                #pragma unroll
                for (int l = 0; l < 16; ++l) {
                    float wrl = rr[l], wil = ri[l];
                    re0[l] += wr0 * wrl + wi0 * wil;   // Re P_{k0,l}
                    im0[l] += wil * wr0 - wrl * wi0;   // Im P_{l,k0}
                    re1[l] += wr1 * wrl + wi1 * wil;
                    im1[l] += wil * wr1 - wrl * wi1;
                }
            }
            float row[16];
            #pragma unroll
            for (int l = 0; l < 16; ++l) {
                float off = (l < k0) ? im0[l] : re0[l];
                row[l] = (l == k0) ? (1.f - 2.f * re0[l]) : (-2.f * RT2 * off);
            }
            *(uint4*)(M + y * KD + k0 * 16)     = pack8(row);
            *(uint4*)(M + y * KD + k0 * 16 + 8) = pack8(row + 8);
            #pragma unroll
            for (int l = 0; l < 16; ++l) {
                float off = (l < k1) ? im1[l] : re1[l];
                row[l] = (l == k1) ? (1.f - 2.f * re1[l]) : (-2.f * RT2 * off);
            }
            *(uint4*)(M + y * KD + k1 * 16)     = pack8(row);
            *(uint4*)(M + y * KD + k1 * 16 + 8) = pack8(row + 8);
        } else {
            // Q producer: one phi per thread.
            int i = ((blk - 32) << 8) + tid;
            float sr[16], si[16];
            #pragma unroll
            for (int k = 0; k < 16; ++k) { sr[k] = (k == 0) ? 1.f : 0.f; si[k] = 0.f; }
            float vec[4];
            #pragma unroll
            for (int q = 0; q < 4; ++q) vec[q] = a[i * 4 + q];
            ansatz(sr, si, vec, P);
            #pragma unroll
            for (int k = 0; k < 16; ++k) {
                float rk = sr[k], ik = si[k];
                float row[16];
                #pragma unroll
                for (int l = 0; l < 16; ++l) {
                    if (l < k)       row[l] = RT2 * (si[l] * rk - sr[l] * ik);
                    else if (l == k) row[l] = rk * rk + ik * ik;
                    else             row[l] = RT2 * (rk * sr[l] + ik * si[l]);
                }
                *(uint4*)(Q + i * KD + k * 16)     = pack8(row);
                *(uint4*)(Q + i * KD + k * 16 + 8) = pack8(row + 8);
            }
        }
        // Arrive: drain + write back this block's stores, then coherent RMW flag.
        __threadfence();
        __syncthreads();
        if (tid == 0)
            (void)__hip_atomic_exchange(&flags[blk], MAGIC, __ATOMIC_RELEASE,
                                        __HIP_MEMORY_SCOPE_AGENT);
    }

    // ---- Barrier: poll ONLY the 3 needed flags via coherent RMW reads ----
    // M rows [bj*64,+64) come from M-blocks 2bj, 2bj+1; Q rows [bi*64,+64)
    // from Q-block 32 + (bi>>2).
    int needed = (tid == 0) ? (2 * bj) : (tid == 1) ? (2 * bj + 1) : (32 + (bi >> 2));
    for (;;) {
        int ok = 1;
        if (tid < 3) {
            unsigned v = __hip_atomic_fetch_or(&flags[needed], 0u, __ATOMIC_RELAXED,
                                               __HIP_MEMORY_SCOPE_AGENT);
            ok = (v == MAGIC);
        }
        if (__syncthreads_count(ok) == 256) break;
        __builtin_amdgcn_s_sleep(32);
    }
    __builtin_amdgcn_fence(__ATOMIC_ACQUIRE, "agent");   // one inv: see producers' Q/M
    __syncthreads();

    // ---------------- Phase 2: 64x64 MFMA tile per block ----------------
    int wave = tid >> 6, lane = tid & 63;
    int wi = wave >> 1, wj = wave & 1;
    int row0 = bi * 64 + wi * 32;
    int col0 = bj * 64 + wj * 32;
    int m16 = lane & 15, quad = lane >> 4;

    const unsigned short* q0 = Q + (size_t)(row0 + m16) * KD + quad * 8;
    const unsigned short* q1 = q0 + 16 * KD;
    const unsigned short* m0 = M + (size_t)(col0 + m16) * KD + quad * 8;
    const unsigned short* m1 = m0 + 16 * KD;

    f32x4 a00 = {0.f,0.f,0.f,0.f}, a01 = {0.f,0.f,0.f,0.f};
    f32x4 a10 = {0.f,0.f,0.f,0.f}, a11 = {0.f,0.f,0.f,0.f};
    #pragma unroll
    for (int kk = 0; kk < 8; ++kk) {
        bf16x8 qa = *(const bf16x8*)(q0 + kk * 32);
        bf16x8 qb = *(const bf16x8*)(q1 + kk * 32);
        bf16x8 ma = *(const bf16x8*)(m0 + kk * 32);
        bf16x8 mb = *(const bf16x8*)(m1 + kk * 32);
        a00 = __builtin_amdgcn_mfma_f32_16x16x32_bf16(qa, ma, a00, 0, 0, 0);
        a01 = __builtin_amdgcn_mfma_f32_16x16x32_bf16(qa, mb, a01, 0, 0, 0);
        a10 = __builtin_amdgcn_mfma_f32_16x16x32_bf16(qb, ma, a10, 0, 0, 0);
        a11 = __builtin_amdgcn_mfma_f32_16x16x32_bf16(qb, mb, a11, 0, 0, 0);
    }
    // C/D layout: col = lane&15, row = quad*4 + r  [HW-verified]
    int col = col0 + m16;
    #pragma unroll
    for (int r = 0; r < 4; ++r) {
        int r0o = row0 + quad * 4 + r;
        int r1o = r0o + 16;
        out[r0o * NB + col]      = fabsf(a00[r]);
        out[r0o * NB + col + 16] = fabsf(a01[r]);
        out[r1o * NB + col]      = fabsf(a10[r]);
        out[r1o * NB + col + 16] = fabsf(a11[r]);
    }
}

extern "C" void kernel_launch(void* const* d_in, const int* in_sizes, int n_in,
                              void* d_out, int out_size, void* d_ws, size_t ws_size,
                              hipStream_t stream) {
    const float* a = (const float*)d_in[0];       // 1024 x 4
    const float* b = (const float*)d_in[1];       // 1024 x 4
    const float* params = (const float*)d_in[2];  // 2 x 4 x 3
    float* out = (float*)d_out;                   // 1024 x 1024

    unsigned short* Q = (unsigned short*)d_ws;            // 1024 x 256 bf16 (512 KB)
    unsigned short* M = Q + (size_t)NA * KD;              // 1024 x 256 bf16 (512 KB)
    unsigned* flags = (unsigned*)((char*)d_ws + (2u << 20));  // 36 words at +2 MB

    qkm_one<<<256, 256, 0, stream>>>(a, b, params, Q, M, flags, out);
}

// Round 8
// 74.231 us; speedup vs baseline: 1.1259x; 1.1259x over previous
//
#include <hip/hip_runtime.h>

// QuantumKernelMethod, two kernels (in-grid barrier abandoned: R5/R6/R7 showed
// any 256-block spin on shared flags costs 55-100us regardless of protocol).
// out[i][j] = |tr(Q_i M_j)|, Q_i = phi phi^dag (phi = V(a_i)|0>),
// M_j = I - 2 P_j, P_j = sum_{p=8..15} w_p w_p^dag (8 basis sims per y).
// Hermitian pack K=256: S[k][l] = diag | sqrt2*Re (k<l) | sqrt2*Im mirror;
// dot(S_Q,S_M) = tr(QM) exactly -> bf16 MFMA GEMM 1024x1024x256.
// R8 change vs R3: phase2 grid 256->1024 blocks (32x32 tiles). R3 ran 1
// block/CU = 1 wave/SIMD -> all load latency exposed; 4 blocks/CU hides it.

#define NA 1024
#define NB 1024
#define KD 256
#define RT2 1.41421356237f

typedef __attribute__((ext_vector_type(8))) short bf16x8;
typedef __attribute__((ext_vector_type(4))) float f32x4;

__device__ __forceinline__ unsigned short f2bf(float x) {
    union { float f; unsigned u; } v; v.f = x;
    unsigned r = v.u + 0x7fffu + ((v.u >> 16) & 1u);  // RNE
    return (unsigned short)(r >> 16);
}

__device__ __forceinline__ uint4 pack8(const float* f) {
    uint4 u;
    u.x = (unsigned)f2bf(f[0]) | ((unsigned)f2bf(f[1]) << 16);
    u.y = (unsigned)f2bf(f[2]) | ((unsigned)f2bf(f[3]) << 16);
    u.z = (unsigned)f2bf(f[4]) | ((unsigned)f2bf(f[5]) << 16);
    u.w = (unsigned)f2bf(f[6]) | ((unsigned)f2bf(f[7]) << 16);
    return u;
}

// State: 16 complex amps, flat index = b0*8+b1*4+b2*2+b3 (wire w -> bit 3-w)
__device__ __forceinline__ void ry_gate(float* sr, float* si, int w, float t) {
    float s, c; __sincosf(0.5f * t, &s, &c);
    int st = 8 >> w;
    #pragma unroll
    for (int b = 0; b < 16; ++b) {
        if (b & st) continue;
        int j = b | st;
        float r0 = sr[b], i0 = si[b], r1 = sr[j], i1 = si[j];
        sr[b] = c * r0 - s * r1;  si[b] = c * i0 - s * i1;
        sr[j] = s * r0 + c * r1;  si[j] = s * i0 + c * i1;
    }
}

__device__ __forceinline__ void rx_gate(float* sr, float* si, int w, float t) {
    float s, c; __sincosf(0.5f * t, &s, &c);
    int st = 8 >> w;
    #pragma unroll
    for (int b = 0; b < 16; ++b) {
        if (b & st) continue;
        int j = b | st;
        float r0 = sr[b], i0 = si[b], r1 = sr[j], i1 = si[j];
        sr[b] = c * r0 + s * i1;  si[b] = c * i0 - s * r1;
        sr[j] = c * r1 + s * i0;  si[j] = c * i1 - s * r0;
    }
}

__device__ __forceinline__ void rz_gate(float* sr, float* si, int w, float t) {
    float s, c; __sincosf(0.5f * t, &s, &c);
    int st = 8 >> w;
    #pragma unroll
    for (int b = 0; b < 16; ++b) {
        if (b & st) continue;
        int j = b | st;
        float r0 = sr[b], i0 = si[b], r1 = sr[j], i1 = si[j];
        sr[b] = c * r0 + s * i0;  si[b] = c * i0 - s * r0;
        sr[j] = c * r1 - s * i1;  si[j] = c * i1 + s * r1;
    }
}

__device__ __forceinline__ void cnot_gate(float* sr, float* si, int cw, int tw) {
    int cs = 8 >> cw, ts = 8 >> tw;
    #pragma unroll
    for (int b = 0; b < 16; ++b) {
        if ((b & cs) && !(b & ts)) {
            int j = b | ts;
            float tr = sr[b]; sr[b] = sr[j]; sr[j] = tr;
            float ti = si[b]; si[b] = si[j]; si[j] = ti;
        }
    }
}

__device__ __forceinline__ void ansatz(float* sr, float* si, const float* vec, const float* P) {
    #pragma unroll
    for (int q = 0; q < 4; ++q) ry_gate(sr, si, q, vec[q]);
    #pragma unroll
    for (int l = 0; l < 2; ++l) {
        #pragma unroll
        for (int q = 0; q < 4; ++q) {
            rx_gate(sr, si, q, P[l * 12 + q * 3 + 0]);
            ry_gate(sr, si, q, P[l * 12 + q * 3 + 1]);
            rz_gate(sr, si, q, P[l * 12 + q * 3 + 2]);
        }
        cnot_gate(sr, si, 0, 1);
        cnot_gate(sr, si, 1, 2);
        cnot_gate(sr, si, 2, 3);
        cnot_gate(sr, si, 3, 0);
    }
}

// Blocks [0,128): M-part, 8 y's/block, 8 threads per y each simulating one
//   basis state p=8+t (wire0 bit set). LDS W[l][sim]: writes lane-contiguous,
//   reads broadcast across t (free) / 2-way across g (free).
// Blocks [128,144): Q-part, 64 i's/block, one thread = one statevector sim.
__global__ __launch_bounds__(64) void qkm_phase1(
    const float* __restrict__ a, const float* __restrict__ b,
    const float* __restrict__ params,
    uint4* __restrict__ Qv, uint4* __restrict__ Mv) {
    float P[24];
    #pragma unroll
    for (int j = 0; j < 24; ++j) P[j] = params[j];
    int tid = threadIdx.x;
    int blk = blockIdx.x;

    if (blk < 128) {
        __shared__ float Wr[16][64];
        __shared__ float Wi[16][64];
        int g = tid >> 3, t = tid & 7;
        int y = (blk << 3) + g;
        float sr[16], si[16];
        #pragma unroll
        for (int k = 0; k < 16; ++k) { sr[k] = (k == 8 + t) ? 1.f : 0.f; si[k] = 0.f; }
        float vec[4];
        #pragma unroll
        for (int q = 0; q < 4; ++q) vec[q] = b[y * 4 + q];
        ansatz(sr, si, vec, P);
        #pragma unroll
        for (int l = 0; l < 16; ++l) { Wr[l][tid] = sr[l]; Wi[l][tid] = si[l]; }
        __syncthreads();
        int base = g << 3;
        // Thread computes rows k = 2t, 2t+1 of S_M for its y.
        #pragma unroll
        for (int kr = 0; kr < 2; ++kr) {
            int k = 2 * t + kr;
            float re[16], im[16];
            #pragma unroll
            for (int l = 0; l < 16; ++l) { re[l] = 0.f; im[l] = 0.f; }
            #pragma unroll
            for (int p2 = 0; p2 < 8; ++p2) {
                float wrk = Wr[k][base + p2], wik = Wi[k][base + p2];
                #pragma unroll
                for (int l = 0; l < 16; ++l) {
                    float wrl = Wr[l][base + p2], wil = Wi[l][base + p2];
                    re[l] += wrk * wrl + wik * wil;   // Re P_kl (sum over sims)
                    im[l] += wil * wrk - wrl * wik;   // Im P_lk
                }
            }
            float row[16];
            #pragma unroll
            for (int l = 0; l < 16; ++l) {
                float off = (l < k) ? im[l] : re[l];
                row[l] = (l == k) ? (1.f - 2.f * re[l]) : (-2.f * RT2 * off);
            }
            uint4* d = Mv + y * 32 + k * 2;
            d[0] = pack8(row); d[1] = pack8(row + 8);
        }
    } else if (blk < 144) {
        int i = ((blk - 128) << 6) + tid;
        float sr[16], si[16];
        #pragma unroll
        for (int k = 0; k < 16; ++k) { sr[k] = (k == 0) ? 1.f : 0.f; si[k] = 0.f; }
        float vec[4];
        #pragma unroll
        for (int q = 0; q < 4; ++q) vec[q] = a[i * 4 + q];
        ansatz(sr, si, vec, P);
        // Q = phi phi^dag: Re Q_kl = rk*rl + ik*il; Im Q_lk = il*rk - rl*ik
        #pragma unroll
        for (int k = 0; k < 16; ++k) {
            float rk = sr[k], ik = si[k];
            float row[16];
            #pragma unroll
            for (int l = 0; l < 16; ++l) {
                if (l < k)       row[l] = RT2 * (si[l] * rk - sr[l] * ik);
                else if (l == k) row[l] = rk * rk + ik * ik;
                else             row[l] = RT2 * (rk * sr[l] + ik * si[l]);
            }
            uint4* d = Qv + i * 32 + k * 2;
            d[0] = pack8(row); d[1] = pack8(row + 8);
        }
    }
}

// Phase 2: out = |Q * M^T|, bf16 MFMA, K=256. 1024 blocks (4 blocks/CU ->
// 4 waves/SIMD latency hiding), 32x32 tile/block, wave = one 16x16 fragment.
// XCD swizzle: bi = (blk&7)*4 + ((blk>>3)&3) -> each XCD's 128 blocks touch a
// 128-row Q band (64 KB) + all M (512 KB), L2-resident.
__global__ __launch_bounds__(256) void qkm_phase2(
    const unsigned short* __restrict__ Q, const unsigned short* __restrict__ M,
    float* __restrict__ out) {
    int wave = threadIdx.x >> 6;
    int lane = threadIdx.x & 63;
    int blk = blockIdx.x;
    int bi = ((blk & 7) << 2) | ((blk >> 3) & 3);   // [0,32)
    int bj = blk >> 5;                              // [0,32)
    int wi = wave >> 1, wj = wave & 1;
    int row0 = bi * 32 + wi * 16;
    int col0 = bj * 32 + wj * 16;
    int m16 = lane & 15, quad = lane >> 4;

    const unsigned short* qrow = Q + (size_t)(row0 + m16) * KD + quad * 8;
    const unsigned short* mrow = M + (size_t)(col0 + m16) * KD + quad * 8;

    f32x4 acc = {0.f, 0.f, 0.f, 0.f};
    #pragma unroll
    for (int kk = 0; kk < 8; ++kk) {
        bf16x8 af = *(const bf16x8*)(qrow + kk * 32);
        bf16x8 bf = *(const bf16x8*)(mrow + kk * 32);
        acc = __builtin_amdgcn_mfma_f32_16x16x32_bf16(af, bf, acc, 0, 0, 0);
    }
    // C/D layout: col = lane&15, row = quad*4 + r  [HW-verified]
    #pragma unroll
    for (int r = 0; r < 4; ++r)
        out[(row0 + quad * 4 + r) * NB + col0 + m16] = fabsf(acc[r]);
}

extern "C" void kernel_launch(void* const* d_in, const int* in_sizes, int n_in,
                              void* d_out, int out_size, void* d_ws, size_t ws_size,
                              hipStream_t stream) {
    const float* a = (const float*)d_in[0];       // 1024 x 4
    const float* b = (const float*)d_in[1];       // 1024 x 4
    const float* params = (const float*)d_in[2];  // 2 x 4 x 3
    float* out = (float*)d_out;                   // 1024 x 1024

    unsigned short* Q = (unsigned short*)d_ws;            // 1024 x 256 bf16 (512 KB)
    unsigned short* M = Q + (size_t)NA * KD;              // 1024 x 256 bf16 (512 KB)

    qkm_phase1<<<144, 64, 0, stream>>>(a, b, params, (uint4*)Q, (uint4*)M);
    qkm_phase2<<<1024, 256, 0, stream>>>(Q, M, out);
}